// Round 13
// baseline (711.777 us; speedup 1.0000x reference)
//
#include <hip/hip_runtime.h>

#define RR 48
#define GG 300
#define HW2 (GG * GG)
#define NPLANE (RR * HW2)
#define NVEC (RR * GG)
#define CC 27
#define TP 64        // points per block tile
#define FROW 148     // featT row stride in words: 16B-aligned rows, 37.9 KB total

// single-pass transpose geometry: all 48 rows x 128 pos per block
#define T2COLS 128
#define T2CHUNK ((HW2 + T2COLS - 1) / T2COLS)  // 704 chunks (tail = 16 pos)
#define T2B3 (3 * T2CHUNK)                     // 2112 plane-transpose blocks
#define T2ROW2 132                             // LDS row stride (words), 16B-aligned
#define VBLK ((3 * NVEC + 255) / 256)          // 169 vec-transpose blocks

typedef float f4v __attribute__((ext_vector_type(4)));  // clang vector: legal
                                                        // for nontemporal builtins

struct Axis { int i0, i1; float f; };

__device__ __forceinline__ Axis axis_interp(float x) {
  float g = x * 2.0f - 1.0f;
  float ih = (g + 1.0f) * 0.5f * (float)(GG - 1);
  int i0 = (int)floorf(ih);
  i0 = i0 < 0 ? 0 : (i0 > GG - 1 ? GG - 1 : i0);
  int i1 = i0 + 1 > GG - 1 ? GG - 1 : i0 + 1;
  Axis a; a.i0 = i0; a.i1 = i1; a.f = ih - (float)i0;
  return a;
}

// ---------------- transpose bodies ----------
// Single block transposes [48][128] -> [128][48]: every 128-B output line is
// written whole by ONE block (round-11's 3-pass split had 3 different XCDs
// each writing 1/3 of every line -> cross-L2 RMW, 1.6 TB/s effective).
__device__ __forceinline__ void plane_transpose48(
    int vb, int t, float* __restrict__ tile,
    const float* __restrict__ p0, const float* __restrict__ p1, const float* __restrict__ p2,
    float* __restrict__ t0, float* __restrict__ t1, float* __restrict__ t2) {
  int plane = vb / T2CHUNK;
  int chunk = vb - plane * T2CHUNK;
  const float* in = (plane == 0) ? p0 : (plane == 1) ? p1 : p2;
  float* outp = (plane == 0) ? t0 : (plane == 1) ? t1 : t2;
  int base = chunk * T2COLS;

  // read: 48 rows x 128 cols, float4-coalesced (512 B per row per block)
  int p4 = t & 31;   // float4 column
  int rg = t >> 5;   // 0..7
  int pos = base + p4 * 4;
  if (pos < HW2) {   // pos multiple of 4, HW2 multiple of 4 -> no straddle
#pragma unroll
    for (int i = 0; i < 6; ++i) {
      int r = i * 8 + rg;
      float4 v = *(const float4*)(in + (size_t)r * HW2 + pos);
      *(float4*)&tile[r * T2ROW2 + p4 * 4] = v;
    }
  }
  __syncthreads();

  // write: 128 rows x 48 ch; per pass 16 channels, c4 pattern is 2-way (free)
  int c4 = t & 3;
  int hwl = t >> 2;  // 0..63
#pragma unroll
  for (int pass = 0; pass < 3; ++pass) {
    int rbase = pass * 16;
#pragma unroll
    for (int jj = 0; jj < 2; ++jj) {
      int hw = jj * 64 + hwl;
      if (base + hw < HW2) {
        f4v w;
        w.x = tile[(rbase + c4 * 4 + 0) * T2ROW2 + hw];
        w.y = tile[(rbase + c4 * 4 + 1) * T2ROW2 + hw];
        w.z = tile[(rbase + c4 * 4 + 2) * T2ROW2 + hw];
        w.w = tile[(rbase + c4 * 4 + 3) * T2ROW2 + hw];
        __builtin_nontemporal_store(
            w, (f4v*)(outp + (size_t)(base + hw) * RR + rbase + c4 * 4));
      }
    }
  }
}

__device__ __forceinline__ void vec_transpose_e(
    int e, const float* __restrict__ v0, const float* __restrict__ v1,
    const float* __restrict__ v2, float* __restrict__ tv0,
    float* __restrict__ tv1, float* __restrict__ tv2) {
  if (e < 3 * NVEC) {
    int v = e / NVEC;
    int rem = e - v * NVEC;
    int i = rem / RR;
    int r = rem - i * RR;
    const float* in = (v == 0) ? v0 : (v == 1) ? v1 : v2;
    float* out = (v == 0) ? tv0 : (v == 1) ? tv1 : tv2;
    out[i * RR + r] = in[r * GG + i];
  }
}

// plane transposes || vec transposes
__global__ void __launch_bounds__(256) transpose_kernel(
    const float* __restrict__ p0, const float* __restrict__ p1, const float* __restrict__ p2,
    float* __restrict__ t0, float* __restrict__ t1, float* __restrict__ t2,
    const float* __restrict__ v0, const float* __restrict__ v1, const float* __restrict__ v2,
    float* __restrict__ tv0, float* __restrict__ tv1, float* __restrict__ tv2) {
  __shared__ float tile[RR * T2ROW2];  // 25.3 KB -> 6 blocks/CU
  int bb = blockIdx.x;
  int t = threadIdx.x;
  if (bb < T2B3) {
    plane_transpose48(bb, t, tile, p0, p1, p2, t0, t1, t2);
  } else {
    vec_transpose_e((bb - T2B3) * 256 + t, v0, v1, v2, tv0, tv1, tv2);
  }
}

// ---------------- fused main (UNSORTED original order) ----------------
// Reads: random gathers served by L3 (planes 124 MB < 256 MB), measured
// ~9.6 TB/s. Writes: coalesced streaming + NON-TEMPORAL so the 108 MB of
// write-once output doesn't evict the plane working set from L2/L3.
__device__ __forceinline__ void gather_seg(const float* __restrict__ P, Axis ai, Axis aj,
                                           const float* __restrict__ V, Axis ak,
                                           int r4, float* __restrict__ dst) {
  float fi = ai.f, fj = aj.f, fk = ak.f;
  float w00 = (1.f - fi) * (1.f - fj);
  float w01 = (1.f - fi) * fj;
  float w10 = fi * (1.f - fj);
  float w11 = fi * fj;
  float omk = 1.f - fk;
  float4 q00 = *(const float4*)(P + (ai.i0 * GG + aj.i0) * RR + r4);
  float4 q01 = *(const float4*)(P + (ai.i0 * GG + aj.i1) * RR + r4);
  float4 q10 = *(const float4*)(P + (ai.i1 * GG + aj.i0) * RR + r4);
  float4 q11 = *(const float4*)(P + (ai.i1 * GG + aj.i1) * RR + r4);
  float4 b0 = *(const float4*)(V + ak.i0 * RR + r4);
  float4 b1 = *(const float4*)(V + ak.i1 * RR + r4);
  float4 o;
  o.x = (w00 * q00.x + w01 * q01.x + w10 * q10.x + w11 * q11.x) * (omk * b0.x + fk * b1.x);
  o.y = (w00 * q00.y + w01 * q01.y + w10 * q10.y + w11 * q11.y) * (omk * b0.y + fk * b1.y);
  o.z = (w00 * q00.z + w01 * q01.z + w10 * q10.z + w11 * q11.z) * (omk * b0.z + fk * b1.z);
  o.w = (w00 * q00.w + w01 * q01.w + w10 * q10.w + w11 * q11.w) * (omk * b0.w + fk * b1.w);
  *(float4*)(dst + r4) = o;  // one ds_write_b128
}

__global__ void __launch_bounds__(256, 4) tensorf_fused(
    const float* __restrict__ xyz,
    const float* __restrict__ Txy, const float* __restrict__ Txz, const float* __restrict__ Tyz,
    const float* __restrict__ Tx, const float* __restrict__ Ty, const float* __restrict__ Tz,
    const float* __restrict__ F, float* __restrict__ out, int n) {
  __shared__ float featT[TP * FROW];  // 37.9 KB -> 4 blocks/CU
  int base = blockIdx.x * TP;
  int tid = threadIdx.x;
  int g = tid >> 4;   // group 0..15, one point per group per iter
  int l = tid & 15;   // lane within group; lanes 0..11 do the loads

  // ---- phase 1: gather + interpolate -> featT[TP][144] ----
#pragma unroll 1
  for (int it = 0; it < TP / 16; ++it) {
    int pl = (it << 4) + g;
    int sp = base + pl;
    if (sp < n) {
      float x = xyz[sp * 3 + 0];   // broadcast within group (L1)
      float y = xyz[sp * 3 + 1];
      float z = xyz[sp * 3 + 2];
      Axis ax = axis_interp(x), ay = axis_interp(y), az = axis_interp(z);
      if (l < 12) {
        int r4 = l << 2;
        float* dst = &featT[pl * FROW];
        gather_seg(Txy, ax, ay, Tz, az, r4, dst + 0 * RR);
        gather_seg(Txz, ax, az, Ty, ay, r4, dst + 1 * RR);
        gather_seg(Tyz, ay, az, Tx, ax, r4, dst + 2 * RR);
      }
    }
  }
  __syncthreads();

  // ---- phase 2: feat[144] @ F[144][27], 4 threads per point ----
  // q wave-uniform via readfirstlane -> F reads stay s_load broadcasts
  // (round-2 lesson). Output writes: contiguous + non-temporal.
  int p = tid & (TP - 1);
  int q = __builtin_amdgcn_readfirstlane(tid >> 6);  // wave-uniform 0..3
  int cbase = (q == 3) ? 20 : q * 7;  // q3 overlaps q2 at c20 to stay in-bounds
  const float* Fh = F + cbase;
  const float* row = &featT[p * FROW];

  float acc[7];
#pragma unroll
  for (int c = 0; c < 7; ++c) acc[c] = 0.f;

#pragma unroll 4
  for (int k4 = 0; k4 < 36; ++k4) {
    float4 fv = *(const float4*)(row + 4 * k4);  // ds_read_b128, conflict-free
    const float* Fr = Fh + (k4 * 4) * CC;
#pragma unroll
    for (int c = 0; c < 7; ++c) {
      acc[c] = fmaf(fv.w, Fr[3 * CC + c],
               fmaf(fv.z, Fr[2 * CC + c],
               fmaf(fv.y, Fr[CC + c],
               fmaf(fv.x, Fr[c], acc[c]))));
    }
  }

  int sp = base + p;
  if (sp < n) {
    float* o = out + (size_t)sp * CC + cbase;  // streaming, coalesced
    if (q != 3) __builtin_nontemporal_store(acc[0], &o[0]);
#pragma unroll
    for (int c = 1; c < 7; ++c) __builtin_nontemporal_store(acc[c], &o[c]);
  }
}

// ---------------- fallback (no workspace) ----------------
__global__ void __launch_bounds__(256) tensorf_naive(
    const float* __restrict__ xyz,
    const float* __restrict__ Pxy, const float* __restrict__ Pxz, const float* __restrict__ Pyz,
    const float* __restrict__ Vx, const float* __restrict__ Vy, const float* __restrict__ Vz,
    const float* __restrict__ F, float* __restrict__ out, int n) {
  int idx = blockIdx.x * blockDim.x + threadIdx.x;
  if (idx >= n) return;
  float x = xyz[idx * 3], y = xyz[idx * 3 + 1], z = xyz[idx * 3 + 2];
  Axis ax = axis_interp(x), ay = axis_interp(y), az = axis_interp(z);
  float acc[CC];
#pragma unroll
  for (int c = 0; c < CC; ++c) acc[c] = 0.f;
  const float* Ps[3] = {Pxy, Pxz, Pyz};
  const float* Vs[3] = {Vz, Vy, Vx};
  Axis A[3][2] = {{ax, ay}, {ax, az}, {ay, az}};
  Axis K[3] = {az, ay, ax};
#pragma unroll 1
  for (int s = 0; s < 3; ++s) {
    Axis ai = A[s][0], aj = A[s][1], ak = K[s];
    float fi = ai.f, fj = aj.f, fk = ak.f;
    float w00 = (1.f - fi) * (1.f - fj), w01 = (1.f - fi) * fj;
    float w10 = fi * (1.f - fj), w11 = fi * fj, omk = 1.f - fk;
#pragma unroll 1
    for (int r = 0; r < RR; ++r) {
      const float* pr = Ps[s] + r * HW2;
      float ft = (w00 * pr[ai.i0 * GG + aj.i0] + w01 * pr[ai.i0 * GG + aj.i1] +
                  w10 * pr[ai.i1 * GG + aj.i0] + w11 * pr[ai.i1 * GG + aj.i1]) *
                 (omk * Vs[s][r * GG + ak.i0] + fk * Vs[s][r * GG + ak.i1]);
      const float* Fr = F + (s * RR + r) * CC;
#pragma unroll
      for (int c = 0; c < CC; ++c) acc[c] = fmaf(ft, Fr[c], acc[c]);
    }
  }
  float* o = out + (size_t)idx * CC;
#pragma unroll
  for (int c = 0; c < CC; ++c) o[c] = acc[c];
}

extern "C" void kernel_launch(void* const* d_in, const int* in_sizes, int n_in,
                              void* d_out, int out_size, void* d_ws, size_t ws_size,
                              hipStream_t stream) {
  const float* xyz = (const float*)d_in[0];
  const float* pxy = (const float*)d_in[1];
  const float* pxz = (const float*)d_in[2];
  const float* pyz = (const float*)d_in[3];
  const float* vx = (const float*)d_in[4];
  const float* vy = (const float*)d_in[5];
  const float* vz = (const float*)d_in[6];
  const float* F = (const float*)d_in[7];
  float* out = (float*)d_out;
  int n = in_sizes[0] / 3;
  int nblk = (n + 255) / 256;

  size_t need = (size_t)(3 * NPLANE + 3 * NVEC) * sizeof(float);

  if (ws_size >= need) {
    float* w = (float*)d_ws;
    float* Txy = w;
    float* Txz = Txy + NPLANE;
    float* Tyz = Txz + NPLANE;
    float* Tx = Tyz + NPLANE;
    float* Ty = Tx + NVEC;
    float* Tz = Ty + NVEC;

    transpose_kernel<<<T2B3 + VBLK, 256, 0, stream>>>(
        pxy, pxz, pyz, Txy, Txz, Tyz, vx, vy, vz, Tx, Ty, Tz);

    int ntile = (n + TP - 1) / TP;
    tensorf_fused<<<ntile, 256, 0, stream>>>(xyz, Txy, Txz, Tyz,
                                             Tx, Ty, Tz, F, out, n);
  } else {
    tensorf_naive<<<nblk, 256, 0, stream>>>(xyz, pxy, pxz, pyz, vx, vy, vz, F, out, n);
  }
}